// Round 10
// baseline (167.721 us; speedup 1.0000x reference)
//
#include <hip/hip_runtime.h>

using u16 = unsigned short;
using u32 = unsigned int;

typedef __bf16 bf16x8 __attribute__((ext_vector_type(8)));
typedef float f32x4 __attribute__((ext_vector_type(4)));

#define T_SEQ 2048
#define NC 1024
#define HDIM 64
#define WINSZ 256
#define QSTEP (2.0f / 255.0f)

__device__ __forceinline__ float b2f(u16 u) {
  u32 v = ((u32)u) << 16;
  return __builtin_bit_cast(float, v);
}
__device__ __forceinline__ u16 f2b(float f) {
  u32 x = __builtin_bit_cast(u32, f);
  u32 r = (x + 0x7fffu + ((x >> 16) & 1u)) >> 16;  // RNE
  return (u16)r;
}
__device__ __forceinline__ float quantize(float v) {
  v = fminf(fmaxf(v, -1.0f), 1.0f);
  return QSTEP * rintf(v / QSTEP);
}
__device__ __forceinline__ void cp16(const void* g, void* l) {
  __builtin_amdgcn_global_load_lds((__attribute__((address_space(1))) void*)g,
                                   (__attribute__((address_space(3))) void*)l, 16, 0, 0);
}

// ---- prep: z=0 transpose w_attn, z=1 transpose w_proj, z=2 convert x (fp32 -> bf16) ----
__global__ __launch_bounds__(256) void k1_prep(const float* __restrict__ x, u16* __restrict__ xb,
                                               const float* __restrict__ wa, u16* __restrict__ wTa,
                                               const float* __restrict__ wp, u16* __restrict__ wTp) {
  if (blockIdx.z == 2) {  // x convert, vectorized x4, grid-stride
    const int nb = gridDim.x * gridDim.y;
    const int bid = blockIdx.y * gridDim.x + blockIdx.x;
    const int n4 = T_SEQ * NC / 4;
    for (int i = bid * 256 + threadIdx.x; i < n4; i += nb * 256) {
      const float4 v = ((const float4*)x)[i];
      ushort4 o;
      o.x = f2b(v.x); o.y = f2b(v.y); o.z = f2b(v.z); o.w = f2b(v.w);
      ((ushort4*)xb)[i] = o;
    }
    return;
  }
  const int iswp = (blockIdx.z == 1);
  if (iswp && blockIdx.x >= 16) return;
  const float* in = iswp ? wp : wa;
  u16* out = iswp ? wTp : wTa;
  const int Cc = iswp ? 1024 : 3072;
  __shared__ u16 tile[64][65];
  const int tc = blockIdx.x * 64, tr = blockIdx.y * 64;
  const int lx = threadIdx.x & 63, ly = threadIdx.x >> 6;
#pragma unroll
  for (int r = ly; r < 64; r += 4)
    tile[r][lx] = f2b(in[(long)(tr + r) * Cc + tc + lx]);
  __syncthreads();
#pragma unroll
  for (int r = ly; r < 64; r += 4) out[(tc + r) * 1024 + tr + lx] = tile[lx][r];
}

// ---- qkv GEMM: 64x128 tile, BK=64, grid (24,32)=768 blocks (3/CU co-resident) ----
// C = xb[2048x1024] * wTa[3072x1024]^T ; fused clip+quantize scatter:
// q -> o0[H][T][HD], k -> o1[H][T][HD], v -> o2[H][HD][T]
__global__ __launch_bounds__(256, 3) void k2_qkv(const u16* __restrict__ A,
                                                 const u16* __restrict__ BT,
                                                 u16* __restrict__ o0, u16* __restrict__ o1,
                                                 u16* __restrict__ o2) {
  __shared__ __align__(16) u16 As[4096];  // [kc:8][row:64][8]   8 KB
  __shared__ __align__(16) u16 Bs[8192];  // [kc:8][row:128][8] 16 KB
  const int tid = threadIdx.x;
  const int lane = tid & 63;
  const int wave = tid >> 6;  // wave = column quarter
  const int ln15 = lane & 15, lq = lane >> 4;
  const int m0 = blockIdx.y * 64, n0 = blockIdx.x * 128;

  // A staging: 512 chunks (2/thread); B staging: 1024 chunks (4/thread)
  const u16* ag[2];
  u16* la[2];
#pragma unroll
  for (int i = 0; i < 2; i++) {
    const int id = tid + i * 256;
    ag[i] = A + (m0 + (id & 63)) * NC + (id >> 6) * 8;
    la[i] = &As[id * 8];
  }
  const u16* bg[4];
  u16* lb[4];
#pragma unroll
  for (int i = 0; i < 4; i++) {
    const int id = tid + i * 256;
    bg[i] = BT + (n0 + (id & 127)) * NC + (id >> 7) * 8;
    lb[i] = &Bs[id * 8];
  }

  f32x4 acc[4][2] = {};

  for (int kt = 0; kt < NC; kt += 64) {
#pragma unroll
    for (int i = 0; i < 2; i++) cp16(ag[i] + kt, la[i]);
#pragma unroll
    for (int i = 0; i < 4; i++) cp16(bg[i] + kt, lb[i]);
    __syncthreads();  // staging complete
#pragma unroll
    for (int s = 0; s < 2; s++) {
      const int kc = s * 4 + lq;
      bf16x8 af[4], bfr[2];
#pragma unroll
      for (int r = 0; r < 4; r++)
        af[r] = *(const bf16x8*)&As[(kc * 64 + r * 16 + ln15) * 8];
#pragma unroll
      for (int c = 0; c < 2; c++)
        bfr[c] = *(const bf16x8*)&Bs[(kc * 128 + wave * 32 + c * 16 + ln15) * 8];
#pragma unroll
      for (int r = 0; r < 4; r++)
#pragma unroll
        for (int c = 0; c < 2; c++)
          acc[r][c] = __builtin_amdgcn_mfma_f32_16x16x32_bf16(af[r], bfr[c], acc[r][c], 0, 0, 0);
    }
    __syncthreads();  // reads done before next tile's cp16
  }

#pragma unroll
  for (int c = 0; c < 2; c++) {
    const int gcol = n0 + wave * 32 + c * 16 + ln15;
    const int p = gcol >> 10;  // 0=q, 1=k, 2=v
    const int h = (gcol & 1023) >> 6;
    const int hd = gcol & 63;
#pragma unroll
    for (int r = 0; r < 4; r++) {
      const int rbase = m0 + r * 16 + lq * 4;
#pragma unroll
      for (int g = 0; g < 4; g++) {
        const u16 b = f2b(quantize(acc[r][c][g]));
        const int row = rbase + g;
        if (p == 0)      o0[(h * T_SEQ + row) * HDIM + hd] = b;
        else if (p == 1) o1[(h * T_SEQ + row) * HDIM + hd] = b;
        else             o2[(h * HDIM + hd) * T_SEQ + row] = b;
      }
    }
  }
}

// ---- attention: one block per (32 queries, head) = 1024 blocks ----
__global__ __launch_bounds__(256, 2) void k3_attn(const u16* __restrict__ qh,
                                                  const u16* __restrict__ kh,
                                                  const u16* __restrict__ vt,
                                                  u16* __restrict__ yq) {
  __shared__ __align__(16) u16 S[32 * 328];  // 21 KB, row stride 656 B
  __shared__ float Linv[32];
  const int tid = threadIdx.x;
  const int lane = tid & 63;
  const int wave = tid >> 6;
  const int ln15 = lane & 15, lq = lane >> 4;
  const int i0 = blockIdx.x * 32;
  const int h = blockIdx.y;
  const int j0 = i0 - 256;  // key col c in [0,320) -> j = j0 + c

  const u16* qb = qh + (h * T_SEQ + i0) * HDIM;
  const u16* kb = kh + h * T_SEQ * HDIM;

  // prefetch V early: latency hides under QK^T + softmax
  const u16* vb = vt + (h * HDIM + wave * 16 + ln15) * T_SEQ;
  bf16x8 vf[10];
#pragma unroll
  for (int kk = 0; kk < 10; kk++) {
    int jb = j0 + kk * 32 + lq * 8;
    if (jb < 0) jb = 0;  // masked region; keep load in-bounds
    vf[kk] = *(const bf16x8*)&vb[jb];
  }

  bf16x8 qf[2][2];
#pragma unroll
  for (int r = 0; r < 2; r++) {
    qf[r][0] = *(const bf16x8*)&qb[(r * 16 + ln15) * HDIM + lq * 8];
    qf[r][1] = *(const bf16x8*)&qb[(r * 16 + ln15) * HDIM + 32 + lq * 8];
  }

  // phase 1: scores -> mask -> scale -> quantize -> S (masked = -inf)
#pragma unroll
  for (int t = 0; t < 5; t++) {
    const int ct = wave + t * 4;
    const int jt = j0 + ct * 16;
    bf16x8 kf0 = {}, kf1 = {};
    if (jt >= 0) {
      kf0 = *(const bf16x8*)&kb[(jt + ln15) * HDIM + lq * 8];
      kf1 = *(const bf16x8*)&kb[(jt + ln15) * HDIM + 32 + lq * 8];
    }
#pragma unroll
    for (int rt = 0; rt < 2; rt++) {
      const bool skip = (ct < rt) || (ct > rt + 16) || (jt < 0);
      f32x4 s = {0.f, 0.f, 0.f, 0.f};
      if (!skip) {
        s = __builtin_amdgcn_mfma_f32_16x16x32_bf16(qf[rt][0], kf0, s, 0, 0, 0);
        s = __builtin_amdgcn_mfma_f32_16x16x32_bf16(qf[rt][1], kf1, s, 0, 0, 0);
      }
      const int j = jt + ln15;
#pragma unroll
      for (int g = 0; g < 4; g++) {
        const int i = i0 + rt * 16 + lq * 4 + g;
        float v = -INFINITY;
        if (!skip && j <= i && j > i - WINSZ) v = quantize(s[g] * 0.125f);
        S[(rt * 16 + lq * 4 + g) * 328 + ct * 16 + ln15] = f2b(v);
      }
    }
  }
  __syncthreads();

  // phase 2: per-row max + unnormalized exp via b128 LDS I/O (8 threads/row)
  {
    const int r = tid >> 3, sg = tid & 7;
    u16* Srow = &S[r * 328 + sg * 40];
    uint4 ch[5];
    float m = -INFINITY;
#pragma unroll
    for (int c = 0; c < 5; c++) {
      ch[c] = *(const uint4*)&Srow[c * 8];
      const u32* w = (const u32*)&ch[c];
#pragma unroll
      for (int d = 0; d < 4; d++) {
        m = fmaxf(m, b2f((u16)(w[d] & 0xffffu)));
        m = fmaxf(m, b2f((u16)(w[d] >> 16)));
      }
    }
    m = fmaxf(m, __shfl_xor(m, 1));
    m = fmaxf(m, __shfl_xor(m, 2));
    m = fmaxf(m, __shfl_xor(m, 4));
    float l = 0.0f;
#pragma unroll
    for (int c = 0; c < 5; c++) {
      u32* w = (u32*)&ch[c];
#pragma unroll
      for (int d = 0; d < 4; d++) {
        const float e0 = __expf(b2f((u16)(w[d] & 0xffffu)) - m);
        const float e1 = __expf(b2f((u16)(w[d] >> 16)) - m);
        l += e0 + e1;
        w[d] = ((u32)f2b(e1) << 16) | f2b(e0);
      }
      *(uint4*)&Srow[c * 8] = ch[c];
    }
    l += __shfl_xor(l, 1);
    l += __shfl_xor(l, 2);
    l += __shfl_xor(l, 4);
    if (sg == 0) Linv[r] = 1.0f / l;
  }
  __syncthreads();

  // phase 3: y = (E @ V^T) * Linv ; wave covers hd block = wave*16
  f32x4 acc[2] = {};
  const int kk_lo = (256 - i0) >> 5;  // i0 < 256 never here? i0 in [0,2016]; clamp:
  const int klo = (i0 < 256) ? kk_lo : 0;
  for (int kk = klo; kk < 10; kk++) {
#pragma unroll
    for (int rt = 0; rt < 2; rt++) {
      const bf16x8 pf = *(const bf16x8*)&S[(rt * 16 + ln15) * 328 + kk * 32 + lq * 8];
      acc[rt] = __builtin_amdgcn_mfma_f32_16x16x32_bf16(pf, vf[kk], acc[rt], 0, 0, 0);
    }
  }
#pragma unroll
  for (int rt = 0; rt < 2; rt++)
#pragma unroll
    for (int g = 0; g < 4; g++) {
      const int row = rt * 16 + lq * 4 + g;
      const int i = i0 + row;
      yq[i * NC + h * HDIM + wave * 16 + ln15] = f2b(quantize(acc[rt][g] * Linv[row]));
    }
}

// ---- proj GEMM: 64x64 tile, BK=128 (8 iters), grid (16,32)=512 blocks, fp32 store ----
__global__ __launch_bounds__(256, 4) void k4_proj(const u16* __restrict__ A,
                                                  const u16* __restrict__ BT,
                                                  float* __restrict__ of) {
  __shared__ __align__(16) u16 As[8192];  // [kc:16][row:64][8] 16 KB
  __shared__ __align__(16) u16 Bs[8192];
  const int tid = threadIdx.x;
  const int lane = tid & 63;
  const int wave = tid >> 6;
  const int wr = wave >> 1, wc = wave & 1;
  const int ln15 = lane & 15, lq = lane >> 4;
  const int m0 = blockIdx.y * 64, n0 = blockIdx.x * 64;

  // staging: 1024 chunks per matrix (4/thread each)
  const u16* ag[4];
  const u16* bg[4];
  u16* la[4];
  u16* lb[4];
#pragma unroll
  for (int i = 0; i < 4; i++) {
    const int id = tid + i * 256;
    const int kc = id >> 6, row = id & 63;
    ag[i] = A + (m0 + row) * NC + kc * 8;
    bg[i] = BT + (n0 + row) * NC + kc * 8;
    la[i] = &As[id * 8];
    lb[i] = &Bs[id * 8];
  }

  f32x4 acc[2][2] = {};

  for (int kt = 0; kt < NC; kt += 128) {
#pragma unroll
    for (int i = 0; i < 4; i++) {
      cp16(ag[i] + kt, la[i]);
      cp16(bg[i] + kt, lb[i]);
    }
    __syncthreads();
#pragma unroll
    for (int s = 0; s < 4; s++) {
      const int kc = s * 4 + lq;
      bf16x8 af[2], bfr[2];
#pragma unroll
      for (int r = 0; r < 2; r++)
        af[r] = *(const bf16x8*)&As[(kc * 64 + wr * 32 + r * 16 + ln15) * 8];
#pragma unroll
      for (int c = 0; c < 2; c++)
        bfr[c] = *(const bf16x8*)&Bs[(kc * 64 + wc * 32 + c * 16 + ln15) * 8];
#pragma unroll
      for (int r = 0; r < 2; r++)
#pragma unroll
        for (int c = 0; c < 2; c++)
          acc[r][c] = __builtin_amdgcn_mfma_f32_16x16x32_bf16(af[r], bfr[c], acc[r][c], 0, 0, 0);
    }
    __syncthreads();
  }

#pragma unroll
  for (int r = 0; r < 2; r++)
#pragma unroll
    for (int g = 0; g < 4; g++) {
      const int row = m0 + wr * 32 + r * 16 + lq * 4 + g;
#pragma unroll
      for (int c = 0; c < 2; c++)
        of[(long)row * NC + n0 + wc * 32 + c * 16 + ln15] = acc[r][c][g];
    }
}

// ---- launch ----
extern "C" void kernel_launch(void* const* d_in, const int* in_sizes, int n_in,
                              void* d_out, int out_size, void* d_ws, size_t ws_size,
                              hipStream_t stream) {
  // bind by element count (order-robust): x=2M, w_attn=3M, w_proj=1M; dtype fp32 (proven R1-R5)
  const void *px = d_in[0], *pwa = d_in[1], *pwp = d_in[2];
  for (int i = 0; i < n_in; i++) {
    if (in_sizes[i] == 2048 * 1024) px = d_in[i];
    else if (in_sizes[i] == 3072 * 1024) pwa = d_in[i];
    else if (in_sizes[i] == 1024 * 1024) pwp = d_in[i];
  }

  char* ws = (char*)d_ws;
  u16* xb  = (u16*)(ws + (1u << 20));    // [2048][1024]  4 MB
  u16* wTa = (u16*)(ws + (5u << 20));    // [3072][1024]  6 MB
  u16* wTp = (u16*)(ws + (11u << 20));   // [1024][1024]  2 MB
  u16* qh  = (u16*)(ws + (13u << 20));   // [16][2048][64] 4 MB
  u16* kh  = (u16*)(ws + (17u << 20));   // 4 MB
  u16* vt  = (u16*)(ws + (21u << 20));   // [16][64][2048] 4 MB
  u16* yq  = (u16*)(ws + (25u << 20));   // [2048][1024]  4 MB

  k1_prep<<<dim3(48, 16, 3), 256, 0, stream>>>((const float*)px, xb, (const float*)pwa, wTa,
                                               (const float*)pwp, wTp);
  k2_qkv<<<dim3(24, 32), 256, 0, stream>>>(xb, wTa, qh, kh, vt);
  k3_attn<<<dim3(64, 16), 256, 0, stream>>>(qh, kh, vt, yq);
  k4_proj<<<dim3(16, 32), 256, 0, stream>>>(yq, wTp, (float*)d_out);
}